// Round 13
// baseline (381.122 us; speedup 1.0000x reference)
//
#include <hip/hip_runtime.h>
#include <math.h>

#define DMODEL 768
#define NHEAD 12
#define DKDIM 64
#define BB 2
#define SS 2048
#define MROWS (BB * SS)          // 4096
#define WELEM (DMODEL * DMODEL)  // 589824
#define MWORDS (SS / 64)         // 32 u64 mask words per row
#define KCHUNK (SS / 2)          // 1024 per K-split group
#define NITH (KCHUNK / 64)       // 16 iterations per wave

typedef unsigned short bf16_t;
typedef __attribute__((ext_vector_type(8))) short s8;   // 8 bf16 = 4 VGPRs (MFMA A/B frag)
typedef __attribute__((ext_vector_type(4))) float f4;   // MFMA C/D frag

#define MFMA(a, b, c) __builtin_amdgcn_mfma_f32_16x16x32_bf16((a), (b), (c), 0, 0, 0)

__device__ __forceinline__ bf16_t f2bf(float f) {   // round-to-nearest-even
    unsigned u = __float_as_uint(f);
    u += 0x7fffu + ((u >> 16) & 1u);
    return (bf16_t)(u >> 16);
}
__device__ __forceinline__ unsigned pack2(float a, float b) {
    return (unsigned)f2bf(a) | ((unsigned)f2bf(b) << 16);
}
// HW packed cvt: attention P-pack only (r6: hurts GEMM staging scheduling).
__device__ __forceinline__ unsigned cvtpk2(float a, float b) {
    unsigned r;
    asm("v_cvt_pk_bf16_f32 %0, %1, %2" : "=v"(r) : "v"(a), "v"(b));
    return r;   // lo = bf16(a), hi = bf16(b)
}
__device__ __forceinline__ s8 ldfrag(const bf16_t* p) {
    union { uint4 u; s8 s; } x;
    x.u = *(const uint4*)p;
    return x.s;
}
// async global->LDS, 16B per lane: LDS dest = wave-uniform base + lane*16.
__device__ __forceinline__ void gload16(const bf16_t* g, bf16_t* l) {
    __builtin_amdgcn_global_load_lds(
        (__attribute__((address_space(1))) void*)g,
        (__attribute__((address_space(3))) void*)l,
        16, 0, 0);
}

// stage 16 consecutive bf16 -> 2 x uint4 (reg-staging path)
__device__ __forceinline__ void ld_stage(const bf16_t* p, uint4& u0, uint4& u1) {
    u0 = *(const uint4*)p;
    u1 = *(const uint4*)(p + 8);
}

// ---------------------------------------------------------------------------
// Weight prepass: fp32 -> bf16, 4 matrices of 768x768. grid (576, 4), 256 thr.
// ---------------------------------------------------------------------------
__global__ void cvt_weights(const float* __restrict__ W0, const float* __restrict__ W1,
                            const float* __restrict__ W2, const float* __restrict__ W3,
                            bf16_t* __restrict__ dst)
{
    const float* src = (blockIdx.y == 0) ? W0 : (blockIdx.y == 1) ? W1
                     : (blockIdx.y == 2) ? W2 : W3;
    bf16_t* d = dst + (size_t)blockIdx.y * WELEM;
    const int i = (blockIdx.x * 256 + threadIdx.x) * 4;
    const float4 v = *(const float4*)(src + i);
    ushort4 h;
    h.x = f2bf(v.x); h.y = f2bf(v.y); h.z = f2bf(v.z); h.w = f2bf(v.w);
    *(ushort4*)(d + i) = h;
}

// ---------------------------------------------------------------------------
// Input prepass: fp32 -> bf16 once (QKV GEMM stages via global_load_lds,
// which cannot convert). grid (3072, 3), 256 thr.
// ---------------------------------------------------------------------------
__global__ __launch_bounds__(256) void cvt_inputs(
    const float* __restrict__ A0, const float* __restrict__ A1,
    const float* __restrict__ A2, bf16_t* __restrict__ dst)
{
    const float* src = (blockIdx.y == 0) ? A0 : (blockIdx.y == 1) ? A1 : A2;
    bf16_t* d = dst + (size_t)blockIdx.y * MROWS * DMODEL;
    const int i = (blockIdx.x * 256 + threadIdx.x) * 4;
    const float4 v = *(const float4*)(src + i);
    ushort4 h;
    h.x = f2bf(v.x); h.y = f2bf(v.y); h.z = f2bf(v.z); h.w = f2bf(v.w);
    *(ushort4*)(d + i) = h;
}

// ---------------------------------------------------------------------------
// Mask prepass: int32 [B,S,S] -> bit-packed u64 words (1 MB, L2-resident).
// ---------------------------------------------------------------------------
__global__ __launch_bounds__(256) void mask_to_bits(
    const int* __restrict__ mask, unsigned long long* __restrict__ mbits)
{
    const size_t gid = (size_t)blockIdx.x * 256 + threadIdx.x;
    const int m = mask[gid];
    const unsigned long long bal = __ballot(m != 0);
    if ((threadIdx.x & 63) == 0) mbits[gid >> 6] = bal;
}

// ---------------------------------------------------------------------------
// QKV GEMM — r11/r8 version (best measured: 128x128 + BK=32 + gload_lds;
// r12's 64x128 variant regressed +6 us, reverted). grid (6, 32, 3), 2.25/CU.
// NEW: z==2 (the V projection) writes its output TRANSPOSED as
// Vt[b][h][d][s] (2 packed u32 stores per fragment) so the attention kernel
// loads V fragments directly from global — no LDS V staging, no barrier.
// ---------------------------------------------------------------------------
__global__ __launch_bounds__(256) void gemm_qkv(
    const bf16_t* __restrict__ A0, const bf16_t* __restrict__ A1, const bf16_t* __restrict__ A2,
    const bf16_t* __restrict__ W0, const bf16_t* __restrict__ W1, const bf16_t* __restrict__ W2,
    const float* __restrict__ bias0, const float* __restrict__ bias1, const float* __restrict__ bias2,
    bf16_t* __restrict__ C0, bf16_t* __restrict__ C1, bf16_t* __restrict__ C2,
    float sc0, float sc1, float sc2)
{
    __shared__ uint4 As4[128 * 4];   // 8 KB, [row][swizzled 16B blk]
    __shared__ uint4 Bs4[128 * 4];

    const int z = blockIdx.z;
    const bf16_t* A    = (z == 0) ? A0 : (z == 1) ? A1 : A2;
    const bf16_t* W    = (z == 0) ? W0 : (z == 1) ? W1 : W2;
    const float*  bias = (z == 0) ? bias0 : (z == 1) ? bias1 : bias2;
    bf16_t*       C    = (z == 0) ? C0 : (z == 1) ? C1 : C2;
    const float   sc   = (z == 0) ? sc0 : (z == 1) ? sc1 : sc2;

    const int tid  = threadIdx.x;
    const int lane = tid & 63;
    const int w    = tid >> 6;
    const int wm   = w & 1;
    const int wn   = w >> 1;
    const int l15  = lane & 15;
    const int quad = lane >> 4;
    const int m0   = blockIdx.y * 128;
    const int n0   = blockIdx.x * 128;

    // per-lane staging sources (pre-swizzled), wave-uniform LDS dests
    const int r0 = tid >> 2,         s0 = (tid & 3) ^ (r0 & 3);
    const int r1 = 64 + (tid >> 2),  s1 = (tid & 3) ^ (r1 & 3);
    const bf16_t* aS0 = A + (size_t)(m0 + r0) * DMODEL + s0 * 8;
    const bf16_t* aS1 = A + (size_t)(m0 + r1) * DMODEL + s1 * 8;
    const bf16_t* wS0 = W + (size_t)(n0 + r0) * DMODEL + s0 * 8;
    const bf16_t* wS1 = W + (size_t)(n0 + r1) * DMODEL + s1 * 8;
    bf16_t* aD0 = (bf16_t*)As4 + w * 512;          // issue 0: chunks 0..255
    bf16_t* aD1 = (bf16_t*)As4 + 2048 + w * 512;   // issue 1: chunks 256..511
    bf16_t* bD0 = (bf16_t*)Bs4 + w * 512;
    bf16_t* bD1 = (bf16_t*)Bs4 + 2048 + w * 512;

    f4 acc[4][4];
    #pragma unroll
    for (int i = 0; i < 4; i++)
        #pragma unroll
        for (int j = 0; j < 4; j++)
            acc[i][j] = (f4){0.f, 0.f, 0.f, 0.f};

    for (int k0 = 0; k0 < DMODEL; k0 += 32) {
        __syncthreads();               // previous iteration's frag reads done
        gload16(aS0 + k0, aD0);
        gload16(aS1 + k0, aD1);
        gload16(wS0 + k0, bD0);
        gload16(wS1 + k0, bD1);
        __syncthreads();               // compiler drains vmcnt(0) before barrier

        s8 af[4], bf[4];
        #pragma unroll
        for (int t = 0; t < 4; t++) {
            const int ar = wm * 64 + t * 16 + l15;
            const int br = wn * 64 + t * 16 + l15;
            union { uint4 u; s8 s; } xa, xb;
            xa.u = As4[ar * 4 + (quad ^ (ar & 3))];
            xb.u = Bs4[br * 4 + (quad ^ (br & 3))];
            af[t] = xa.s;
            bf[t] = xb.s;
        }
        #pragma unroll
        for (int mt = 0; mt < 4; mt++)
            #pragma unroll
            for (int nt = 0; nt < 4; nt++)
                acc[mt][nt] = MFMA(af[mt], bf[nt], acc[mt][nt]);
    }

    // epilogue: row = m0+64wm+16mt+4quad+reg, col = n0+64wn+16nt+l15
    #pragma unroll
    for (int mt = 0; mt < 4; mt++) {
        const int grow = m0 + wm * 64 + mt * 16 + quad * 4;   // rows grow..+3
        #pragma unroll
        for (int nt = 0; nt < 4; nt++) {
            const int col = n0 + wn * 64 + nt * 16 + l15;
            const float bb = bias[col];
            if (z == 2) {
                // transposed write: Vt[b][h][d][s], s = grow..grow+3 (sc==1)
                const int bidx = grow >> 11;
                const int sr   = grow & (SS - 1);
                const float v0 = acc[mt][nt][0] + bb;
                const float v1 = acc[mt][nt][1] + bb;
                const float v2 = acc[mt][nt][2] + bb;
                const float v3 = acc[mt][nt][3] + bb;
                unsigned* dst = (unsigned*)(C +
                    ((size_t)(bidx * NHEAD + (col >> 6)) * DKDIM + (col & 63)) * SS + sr);
                dst[0] = pack2(v0, v1);
                dst[1] = pack2(v2, v3);
            } else {
                #pragma unroll
                for (int reg = 0; reg < 4; reg++) {
                    C[(size_t)(grow + reg) * DMODEL + col] =
                        f2bf((acc[mt][nt][reg] + bb) * sc);
                }
            }
        }
    }
}

// ---------------------------------------------------------------------------
// Output-projection GEMM — r11 version (verified win): 64x128 tile,
// grid (6, 64) = 384 blocks (1.5/CU), reg-staged BK=32 with XOR swizzle.
// ---------------------------------------------------------------------------
__global__ __launch_bounds__(256) void gemm_out(
    const bf16_t* __restrict__ A, const bf16_t* __restrict__ W,
    const float* __restrict__ bias, float* __restrict__ C)
{
    __shared__ uint4 As4[64 * 4];    // 4 KB
    __shared__ uint4 Bs4[128 * 4];   // 8 KB

    const int tid  = threadIdx.x;
    const int lane = tid & 63;
    const int w    = tid >> 6;       // 0..3: 32-col strip
    const int l15  = lane & 15;
    const int quad = lane >> 4;
    const int m0   = blockIdx.y * 64;
    const int n0   = blockIdx.x * 128;

    const int srow  = tid >> 1;      // 0..127 (B rows; A uses 0..63)
    const int shalf = tid & 1;
    const int sw    = srow & 3;
    const int arow  = (tid < 128) ? srow : 0;   // clamp: threads >=128 never use A

    const bf16_t* aptr = A + (size_t)(m0 + arow) * DMODEL + shalf * 16;
    const bf16_t* wptr = W + (size_t)(n0 + srow) * DMODEL + shalf * 16;

    f4 acc[4][2];
    #pragma unroll
    for (int i = 0; i < 4; i++)
        #pragma unroll
        for (int j = 0; j < 2; j++)
            acc[i][j] = (f4){0.f, 0.f, 0.f, 0.f};

    for (int k0 = 0; k0 < DMODEL; k0 += 32) {
        uint4 au0, au1, bu0, bu1;
        if (tid < 128) ld_stage(aptr + k0, au0, au1);
        ld_stage(wptr + k0, bu0, bu1);
        __syncthreads();               // previous step's frag reads done
        if (tid < 128) {
            As4[srow * 4 + ((shalf * 2 + 0) ^ sw)] = au0;
            As4[srow * 4 + ((shalf * 2 + 1) ^ sw)] = au1;
        }
        Bs4[srow * 4 + ((shalf * 2 + 0) ^ sw)] = bu0;
        Bs4[srow * 4 + ((shalf * 2 + 1) ^ sw)] = bu1;
        __syncthreads();

        s8 af[4], bf[2];
        #pragma unroll
        for (int t = 0; t < 4; t++) {
            const int ar = t * 16 + l15;
            union { uint4 u; s8 s; } xa;
            xa.u = As4[ar * 4 + (quad ^ (ar & 3))];
            af[t] = xa.s;
        }
        #pragma unroll
        for (int nt = 0; nt < 2; nt++) {
            const int br = w * 32 + nt * 16 + l15;
            union { uint4 u; s8 s; } xb;
            xb.u = Bs4[br * 4 + (quad ^ (br & 3))];
            bf[nt] = xb.s;
        }
        #pragma unroll
        for (int mt = 0; mt < 4; mt++)
            #pragma unroll
            for (int nt = 0; nt < 2; nt++)
                acc[mt][nt] = MFMA(af[mt], bf[nt], acc[mt][nt]);
    }

    // epilogue: row = m0+16mt+4quad+reg, col = n0+32w+16nt+l15
    #pragma unroll
    for (int mt = 0; mt < 4; mt++) {
        #pragma unroll
        for (int nt = 0; nt < 2; nt++) {
            const int col = n0 + w * 32 + nt * 16 + l15;
            const float bb = bias[col];
            #pragma unroll
            for (int reg = 0; reg < 4; reg++) {
                const int row = m0 + mt * 16 + quad * 4 + reg;
                C[(size_t)row * DMODEL + col] = acc[mt][nt][reg] + bb;
            }
        }
    }
}

// ---------------------------------------------------------------------------
// MFMA flash attention — BARRIER-FREE main loop + in-block K-split x2.
// grid (S/64, H, B), 512 thr = 8 waves: wq = w&3 picks the 16-q-row subtile,
// ws = w>>2 picks the K half (16 iters each). ZERO in-loop barriers, ZERO
// in-loop LDS:
//  - V fragments load directly from pre-transposed Vt[b][h][d][s], PREFETCHED
//    a full iteration ahead (r4's failure was unprefetched Vt loads sitting
//    in the PV chain; r12 refuted the barrier-drain theory, so the V-staging
//    structure itself — pack + ds_write + ds_read + barrier — is what goes).
//  - K frags + mask word prefetched one iter ahead (r6-proven).
//  - swapped QK^T (S^T in regs), bit-mask (1 u64/iter), shuffle-PV, fixed-max
//    exp2 softmax (Q pre-scaled 0.125*log2e) — all r9-proven.
//  - K-split merge is TRIVIAL under fixed-max: partials are additive (no
//    max/rescale). ws=1 deposits raw O + l in LDS; ONE barrier; ws=0 adds,
//    normalizes by 1/(lA+lB), stores. (r1/r2/r3's K-split failures were
//    spill, barrier-coupling, and HBM partials — all structurally absent.)
// Waves/CU 12 -> 16 (VGPR must stay <=128; plain __launch_bounds__).
// ---------------------------------------------------------------------------
__global__ __launch_bounds__(512) void attn_mfma(
    const bf16_t* __restrict__ Q, const bf16_t* __restrict__ K,
    const bf16_t* __restrict__ Vt, const unsigned long long* __restrict__ mbits,
    bf16_t* __restrict__ O)
{
    __shared__ float Osh[4][16][68];   // merge buffer: [wq][q-row][d] (17 KB)
    __shared__ float Lsh[4][16];

    const int tid  = threadIdx.x;
    const int lane = tid & 63;
    const int w    = tid >> 6;            // 0..7
    const int wq   = w & 3;               // q sub-tile
    const int ws   = w >> 2;              // K-split group
    const int l15  = lane & 15;
    const int quad = lane >> 4;
    const int q0   = blockIdx.x * 64;
    const int h    = blockIdx.y;
    const int b    = blockIdx.z;
    const int ks   = ws * KCHUNK;
    const size_t base = ((size_t)b * SS) * DMODEL + (size_t)h * DKDIM;
    const bf16_t* vtb = Vt + (size_t)(b * NHEAD + h) * DKDIM * SS;   // [d][s]

    // Q as B-operand (col q = l15); K as A-operand (row k = l15)
    const bf16_t* qrow = Q + base + (size_t)(q0 + wq * 16 + l15) * DMODEL + quad * 8;
    const s8 qf0 = ldfrag(qrow);
    const s8 qf1 = ldfrag(qrow + 32);

    f4 oacc[4];
    #pragma unroll
    for (int i = 0; i < 4; i++) oacc[i] = (f4){0.f, 0.f, 0.f, 0.f};
    float l_part = 0.0f;                  // denominator partial for q = l15

    const bf16_t* kbase = K + base + (size_t)l15 * DMODEL + quad * 8;
    // V frag base: row d = dt*16+l15, col s = ks + it*64 + kt*32 + quad*8
    const bf16_t* vfb = vtb + (size_t)l15 * SS + ks + quad * 8;

    // one u64 mask word per iter: row q = l15, word (ks>>6)+it
    const unsigned long long* mbase =
        mbits + ((size_t)b * SS + (q0 + wq * 16 + l15)) * MWORDS + (ks >> 6);

    // loop-invariant shuffle sources + select (r7/r9-verified algebra)
    const int sA  = l15 + (((2 * quad) & 3) << 4);
    const int sB  = l15 + (((2 * quad + 1) & 3) << 4);
    const bool hiQ = (quad & 2) != 0;

    // prologue: prefetch K frags, mask word, V frags for iteration 0
    s8 kf0[4], kf1[4], vf0[4], vf1[4];
    unsigned long long mw;
    #pragma unroll
    for (int nt = 0; nt < 4; nt++) {
        const bf16_t* krow = kbase + (size_t)(ks + nt * 16) * DMODEL;
        kf0[nt] = ldfrag(krow);
        kf1[nt] = ldfrag(krow + 32);
    }
    mw = mbase[0];
    #pragma unroll
    for (int dt = 0; dt < 4; dt++) {
        vf0[dt] = ldfrag(vfb + (size_t)(dt * 16) * SS);
        vf1[dt] = ldfrag(vfb + (size_t)(dt * 16) * SS + 32);
    }

    for (int it = 0; it < NITH; ++it) {
        const int k0 = ks + it * 64;

        // swapped QK^T on prefetched K fragments: sacc = S^T tiles
        f4 sacc[4];
        __builtin_amdgcn_s_setprio(1);
        #pragma unroll
        for (int nt = 0; nt < 4; nt++) {
            f4 zz = {0.f, 0.f, 0.f, 0.f};
            zz = MFMA(kf0[nt], qf0, zz);
            zz = MFMA(kf1[nt], qf1, zz);
            sacc[nt] = zz;
        }
        __builtin_amdgcn_s_setprio(0);

        // prefetch K frags + mask word for it+1 (hidden under softmax+PV)
        const unsigned long long mwc = mw;
        if (it + 1 < NITH) {
            #pragma unroll
            for (int nt = 0; nt < 4; nt++) {
                const bf16_t* krow = kbase + (size_t)(k0 + 64 + nt * 16) * DMODEL;
                kf0[nt] = ldfrag(krow);
                kf1[nt] = ldfrag(krow + 32);
            }
            mw = mbase[it + 1];
        }

        // fixed-max softmax: p = maskbit ? exp2(s) : 0, pack k-pairs in-lane.
        const unsigned ml = ((unsigned)mwc) >> (quad * 4);
        const unsigned mh = ((unsigned)(mwc >> 32)) >> (quad * 4);
        unsigned wlo[4], whi[4];
        #pragma unroll
        for (int nt = 0; nt < 4; nt++) {
            const unsigned mm = (nt & 2) ? mh : ml;
            const int shft = (nt & 1) * 16;
            const float p0 = ((mm >> (shft + 0)) & 1u) ? __builtin_exp2f(sacc[nt][0]) : 0.0f;
            const float p1 = ((mm >> (shft + 1)) & 1u) ? __builtin_exp2f(sacc[nt][1]) : 0.0f;
            const float p2 = ((mm >> (shft + 2)) & 1u) ? __builtin_exp2f(sacc[nt][2]) : 0.0f;
            const float p3 = ((mm >> (shft + 3)) & 1u) ? __builtin_exp2f(sacc[nt][3]) : 0.0f;
            l_part += (p0 + p1) + (p2 + p3);
            wlo[nt] = cvtpk2(p0, p1);
            whi[nt] = cvtpk2(p2, p3);
        }

        // P -> PV A-frag among the 4 lanes sharing l15, then PV on
        // prefetched V fragments (kt unrolled -> vf0/vf1 static)
        #pragma unroll
        for (int kt = 0; kt < 2; kt++) {
            const unsigned a0 = (unsigned)__shfl((int)wlo[2 * kt],     sA, 64);
            const unsigned a1 = (unsigned)__shfl((int)wlo[2 * kt + 1], sA, 64);
            const unsigned b0 = (unsigned)__shfl((int)whi[2 * kt],     sA, 64);
            const unsigned b1 = (unsigned)__shfl((int)whi[2 * kt + 1], sA, 64);
            const unsigned c0 = (unsigned)__shfl((int)wlo[2 * kt],     sB, 64);
            const unsigned c1 = (unsigned)__shfl((int)wlo[2 * kt + 1], sB, 64);
            const unsigned d0 = (unsigned)__shfl((int)whi[2 * kt],     sB, 64);
            const unsigned d1 = (unsigned)__shfl((int)whi[2 * kt + 1], sB, 64);
            union { uint4 u; s8 s; } pf;
            pf.u.x = hiQ ? a1 : a0;
            pf.u.y = hiQ ? b1 : b0;
            pf.u.z = hiQ ? c1 : c0;
            pf.u.w = hiQ ? d1 : d0;

            __builtin_amdgcn_s_setprio(1);
            if (kt == 0) {
                #pragma unroll
                for (int dt = 0; dt < 4; dt++)
                    oacc[dt] = MFMA(pf.s, vf0[dt], oacc[dt]);
            } else {
                #pragma unroll
                for (int dt = 0; dt < 4; dt++)
                    oacc[dt] = MFMA(pf.s, vf1[dt], oacc[dt]);
            }
            __builtin_amdgcn_s_setprio(0);
        }

        // prefetch V fragments for it+1 (consumed a full iteration later)
        if (it + 1 < NITH) {
            #pragma unroll
            for (int dt = 0; dt < 4; dt++) {
                vf0[dt] = ldfrag(vfb + (size_t)(dt * 16) * SS + (it + 1) * 64);
                vf1[dt] = ldfrag(vfb + (size_t)(dt * 16) * SS + (it + 1) * 64 + 32);
            }
        }
        // NO barrier, NO LDS: waves fully independent
    }

    // intra-wave l reduce over the 4 quads (all lanes end with the full sum)
    l_part += __shfl_xor(l_part, 16, 64);
    l_part += __shfl_xor(l_part, 32, 64);

    // ---- K-split merge (fixed-max => partials are simply additive) ----
    if (ws == 1) {
        #pragma unroll
        for (int dt = 0; dt < 4; dt++)
            #pragma unroll
            for (int reg = 0; reg < 4; reg++)
                Osh[wq][quad * 4 + reg][dt * 16 + l15] = oacc[dt][reg];
        if (quad == 0) Lsh[wq][l15] = l_part;
    }
    __syncthreads();

    if (ws == 0) {
        const float inv = 1.0f / (l_part + Lsh[wq][l15]);   // for q-row l15
        #pragma unroll
        for (int dt = 0; dt < 4; dt++)
            #pragma unroll
            for (int reg = 0; reg < 4; reg++)
                oacc[dt][reg] += Osh[wq][quad * 4 + reg][dt * 16 + l15];

        #pragma unroll
        for (int reg = 0; reg < 4; reg++) {
            const float invq = __shfl(inv, (quad << 4) + quad * 4 + reg, 64);
            const size_t row = q0 + wq * 16 + quad * 4 + reg;
            #pragma unroll
            for (int dt = 0; dt < 4; dt++) {
                O[base + row * DMODEL + dt * 16 + l15] = f2bf(oacc[dt][reg] * invq);
            }
        }
    }
}

// ---------------------------------------------------------------------------
extern "C" void kernel_launch(void* const* d_in, const int* in_sizes, int n_in,
                              void* d_out, int out_size, void* d_ws, size_t ws_size,
                              hipStream_t stream)
{
    const float* q    = (const float*)d_in[0];
    const float* k    = (const float*)d_in[1];
    const float* v    = (const float*)d_in[2];
    const int*   mask = (const int*)  d_in[3];
    const float* Wq   = (const float*)d_in[4];
    const float* bq   = (const float*)d_in[5];
    const float* Wk   = (const float*)d_in[6];
    const float* bk   = (const float*)d_in[7];
    const float* Wv   = (const float*)d_in[8];
    const float* bv   = (const float*)d_in[9];
    const float* Wo   = (const float*)d_in[10];
    const float* bo   = (const float*)d_in[11];
    float* out = (float*)d_out;

    // workspace (~50 MB): 4 bf16 planes (25.2 MB) + 4 bf16 weights (4.7 MB)
    //                    + 3 bf16 input planes (18.9 MB) + mbits (1 MB)
    bf16_t* wsb = (bf16_t*)d_ws;
    const size_t plane = (size_t)MROWS * DMODEL;   // 3,145,728
    bf16_t* Qp  = wsb;
    bf16_t* Kp  = wsb + plane;
    bf16_t* Vtp = wsb + 2 * plane;        // V projection output, TRANSPOSED [b][h][d][s]
    bf16_t* Ctx = wsb + 3 * plane;
    bf16_t* Wqb = wsb + 4 * plane;
    bf16_t* Wkb = Wqb + WELEM;
    bf16_t* Wvb = Wkb + WELEM;
    bf16_t* Wob = Wvb + WELEM;
    bf16_t* Abf = Wob + WELEM;            // 3 bf16 input planes
    unsigned long long* mbits = (unsigned long long*)(Abf + 3 * plane);

    cvt_weights<<<dim3(WELEM / 1024, 4), 256, 0, stream>>>(Wq, Wk, Wv, Wo, Wqb);
    cvt_inputs<<<dim3((int)(plane / 1024), 3), 256, 0, stream>>>(q, k, v, Abf);
    mask_to_bits<<<dim3((BB * SS * SS) / 256), 256, 0, stream>>>(mask, mbits);

    // fused Q/K/V projections (r11 structure; V written transposed);
    // Q pre-scaled by 0.125*log2(e) for the exp2 softmax
    gemm_qkv<<<dim3(DMODEL / 128, MROWS / 128, 3), 256, 0, stream>>>(
        Abf, Abf + plane, Abf + 2 * plane, Wqb, Wkb, Wvb, bq, bk, bv,
        Qp, Kp, Vtp, 0.125f * 1.44269504f, 1.0f, 1.0f);

    // barrier-free K-split flash attention: grid (32, 12, 2), 512 thr
    attn_mfma<<<dim3(SS / 64, NHEAD, BB), 512, 0, stream>>>(Qp, Kp, Vtp, mbits, Ctx);

    // output projection: 64x128 tile, grid (6, 64) = 384 blocks (1.5/CU)
    gemm_out<<<dim3(DMODEL / 128, MROWS / 64), 256, 0, stream>>>(Ctx, Wob, bo, out);
}

// Round 15
// 306.404 us; speedup vs baseline: 1.2439x; 1.2439x over previous
//
#include <hip/hip_runtime.h>
#include <math.h>

#define DMODEL 768
#define NHEAD 12
#define DKDIM 64
#define BB 2
#define SS 2048
#define MROWS (BB * SS)          // 4096
#define WELEM (DMODEL * DMODEL)  // 589824
#define MWORDS (SS / 64)         // 32 u64 mask words per row
#define NIT (SS / 64)            // 32 K-tiles

typedef unsigned short bf16_t;
typedef __attribute__((ext_vector_type(8))) short s8;   // 8 bf16 = 4 VGPRs (MFMA A/B frag)
typedef __attribute__((ext_vector_type(4))) float f4;   // MFMA C/D frag

#define MFMA(a, b, c) __builtin_amdgcn_mfma_f32_16x16x32_bf16((a), (b), (c), 0, 0, 0)

__device__ __forceinline__ bf16_t f2bf(float f) {   // round-to-nearest-even
    unsigned u = __float_as_uint(f);
    u += 0x7fffu + ((u >> 16) & 1u);
    return (bf16_t)(u >> 16);
}
// HW packed cvt: attention P-pack only (r6: hurts GEMM staging scheduling).
__device__ __forceinline__ unsigned cvtpk2(float a, float b) {
    unsigned r;
    asm("v_cvt_pk_bf16_f32 %0, %1, %2" : "=v"(r) : "v"(a), "v"(b));
    return r;   // lo = bf16(a), hi = bf16(b)
}
__device__ __forceinline__ s8 ldfrag(const bf16_t* p) {
    union { uint4 u; s8 s; } x;
    x.u = *(const uint4*)p;
    return x.s;
}
// async global->LDS, 16B per lane: LDS dest = wave-uniform base + lane*16.
__device__ __forceinline__ void gload16(const bf16_t* g, bf16_t* l) {
    __builtin_amdgcn_global_load_lds(
        (__attribute__((address_space(1))) void*)g,
        (__attribute__((address_space(3))) void*)l,
        16, 0, 0);
}

// stage 16 consecutive bf16 -> 2 x uint4 (reg-staging path)
__device__ __forceinline__ void ld_stage(const bf16_t* p, uint4& u0, uint4& u1) {
    u0 = *(const uint4*)p;
    u1 = *(const uint4*)(p + 8);
}

// ---------------------------------------------------------------------------
// Weight prepass: fp32 -> bf16, 4 matrices of 768x768. grid (576, 4), 256 thr.
// ---------------------------------------------------------------------------
__global__ void cvt_weights(const float* __restrict__ W0, const float* __restrict__ W1,
                            const float* __restrict__ W2, const float* __restrict__ W3,
                            bf16_t* __restrict__ dst)
{
    const float* src = (blockIdx.y == 0) ? W0 : (blockIdx.y == 1) ? W1
                     : (blockIdx.y == 2) ? W2 : W3;
    bf16_t* d = dst + (size_t)blockIdx.y * WELEM;
    const int i = (blockIdx.x * 256 + threadIdx.x) * 4;
    const float4 v = *(const float4*)(src + i);
    ushort4 h;
    h.x = f2bf(v.x); h.y = f2bf(v.y); h.z = f2bf(v.z); h.w = f2bf(v.w);
    *(ushort4*)(d + i) = h;
}

// ---------------------------------------------------------------------------
// Input prepass: fp32 -> bf16 once (QKV GEMM stages via global_load_lds,
// which cannot convert). grid (3072, 3), 256 thr.
// ---------------------------------------------------------------------------
__global__ __launch_bounds__(256) void cvt_inputs(
    const float* __restrict__ A0, const float* __restrict__ A1,
    const float* __restrict__ A2, bf16_t* __restrict__ dst)
{
    const float* src = (blockIdx.y == 0) ? A0 : (blockIdx.y == 1) ? A1 : A2;
    bf16_t* d = dst + (size_t)blockIdx.y * MROWS * DMODEL;
    const int i = (blockIdx.x * 256 + threadIdx.x) * 4;
    const float4 v = *(const float4*)(src + i);
    ushort4 h;
    h.x = f2bf(v.x); h.y = f2bf(v.y); h.z = f2bf(v.z); h.w = f2bf(v.w);
    *(ushort4*)(d + i) = h;
}

// ---------------------------------------------------------------------------
// Mask prepass: int32 [B,S,S] -> bit-packed u64 words (1 MB, L2-resident).
// ---------------------------------------------------------------------------
__global__ __launch_bounds__(256) void mask_to_bits(
    const int* __restrict__ mask, unsigned long long* __restrict__ mbits)
{
    const size_t gid = (size_t)blockIdx.x * 256 + threadIdx.x;
    const int m = mask[gid];
    const unsigned long long bal = __ballot(m != 0);
    if ((threadIdx.x & 63) == 0) mbits[gid >> 6] = bal;
}

// ---------------------------------------------------------------------------
// QKV GEMM — r8/r11 version (best measured): 128x128 tile, BK=32 +
// global_load_lds staging. G21 both-sides swizzle: linear LDS dest +
// pre-swizzled per-lane source (blk^(row&3)) + swizzled frag read.
// grid (6, 32, 3) = 576 blocks, 2.25/CU.
// ---------------------------------------------------------------------------
__global__ __launch_bounds__(256) void gemm_qkv(
    const bf16_t* __restrict__ A0, const bf16_t* __restrict__ A1, const bf16_t* __restrict__ A2,
    const bf16_t* __restrict__ W0, const bf16_t* __restrict__ W1, const bf16_t* __restrict__ W2,
    const float* __restrict__ bias0, const float* __restrict__ bias1, const float* __restrict__ bias2,
    bf16_t* __restrict__ C0, bf16_t* __restrict__ C1, bf16_t* __restrict__ C2,
    float sc0, float sc1, float sc2)
{
    __shared__ uint4 As4[128 * 4];   // 8 KB, [row][swizzled 16B blk]
    __shared__ uint4 Bs4[128 * 4];

    const int z = blockIdx.z;
    const bf16_t* A    = (z == 0) ? A0 : (z == 1) ? A1 : A2;
    const bf16_t* W    = (z == 0) ? W0 : (z == 1) ? W1 : W2;
    const float*  bias = (z == 0) ? bias0 : (z == 1) ? bias1 : bias2;
    bf16_t*       C    = (z == 0) ? C0 : (z == 1) ? C1 : C2;
    const float   sc   = (z == 0) ? sc0 : (z == 1) ? sc1 : sc2;

    const int tid  = threadIdx.x;
    const int lane = tid & 63;
    const int w    = tid >> 6;
    const int wm   = w & 1;
    const int wn   = w >> 1;
    const int l15  = lane & 15;
    const int quad = lane >> 4;
    const int m0   = blockIdx.y * 128;
    const int n0   = blockIdx.x * 128;

    // per-lane staging sources (pre-swizzled), wave-uniform LDS dests
    const int r0 = tid >> 2,         s0 = (tid & 3) ^ (r0 & 3);
    const int r1 = 64 + (tid >> 2),  s1 = (tid & 3) ^ (r1 & 3);
    const bf16_t* aS0 = A + (size_t)(m0 + r0) * DMODEL + s0 * 8;
    const bf16_t* aS1 = A + (size_t)(m0 + r1) * DMODEL + s1 * 8;
    const bf16_t* wS0 = W + (size_t)(n0 + r0) * DMODEL + s0 * 8;
    const bf16_t* wS1 = W + (size_t)(n0 + r1) * DMODEL + s1 * 8;
    bf16_t* aD0 = (bf16_t*)As4 + w * 512;          // issue 0: chunks 0..255
    bf16_t* aD1 = (bf16_t*)As4 + 2048 + w * 512;   // issue 1: chunks 256..511
    bf16_t* bD0 = (bf16_t*)Bs4 + w * 512;
    bf16_t* bD1 = (bf16_t*)Bs4 + 2048 + w * 512;

    f4 acc[4][4];
    #pragma unroll
    for (int i = 0; i < 4; i++)
        #pragma unroll
        for (int j = 0; j < 4; j++)
            acc[i][j] = (f4){0.f, 0.f, 0.f, 0.f};

    for (int k0 = 0; k0 < DMODEL; k0 += 32) {
        __syncthreads();               // previous iteration's frag reads done
        gload16(aS0 + k0, aD0);
        gload16(aS1 + k0, aD1);
        gload16(wS0 + k0, bD0);
        gload16(wS1 + k0, bD1);
        __syncthreads();               // compiler drains vmcnt(0) before barrier

        s8 af[4], bf[4];
        #pragma unroll
        for (int t = 0; t < 4; t++) {
            const int ar = wm * 64 + t * 16 + l15;
            const int br = wn * 64 + t * 16 + l15;
            union { uint4 u; s8 s; } xa, xb;
            xa.u = As4[ar * 4 + (quad ^ (ar & 3))];
            xb.u = Bs4[br * 4 + (quad ^ (br & 3))];
            af[t] = xa.s;
            bf[t] = xb.s;
        }
        #pragma unroll
        for (int mt = 0; mt < 4; mt++)
            #pragma unroll
            for (int nt = 0; nt < 4; nt++)
                acc[mt][nt] = MFMA(af[mt], bf[nt], acc[mt][nt]);
    }

    // epilogue: row = m0+64wm+16mt+4quad+reg, col = n0+64wn+16nt+l15
    #pragma unroll
    for (int mt = 0; mt < 4; mt++) {
        #pragma unroll
        for (int nt = 0; nt < 4; nt++) {
            const int col = n0 + wn * 64 + nt * 16 + l15;
            const float bb = bias[col];
            #pragma unroll
            for (int reg = 0; reg < 4; reg++) {
                const int row = m0 + wm * 64 + mt * 16 + quad * 4 + reg;
                C[(size_t)row * DMODEL + col] = f2bf((acc[mt][nt][reg] + bb) * sc);
            }
        }
    }
}

// ---------------------------------------------------------------------------
// Output-projection GEMM — r11 version (verified win): 64x128 tile,
// grid (6, 64) = 384 blocks (1.5/CU), reg-staged BK=32 with XOR swizzle.
// ---------------------------------------------------------------------------
__global__ __launch_bounds__(256) void gemm_out(
    const bf16_t* __restrict__ A, const bf16_t* __restrict__ W,
    const float* __restrict__ bias, float* __restrict__ C)
{
    __shared__ uint4 As4[64 * 4];    // 4 KB
    __shared__ uint4 Bs4[128 * 4];   // 8 KB

    const int tid  = threadIdx.x;
    const int lane = tid & 63;
    const int w    = tid >> 6;       // 0..3: 32-col strip
    const int l15  = lane & 15;
    const int quad = lane >> 4;
    const int m0   = blockIdx.y * 64;
    const int n0   = blockIdx.x * 128;

    const int srow  = tid >> 1;      // 0..127 (B rows; A uses 0..63)
    const int shalf = tid & 1;
    const int sw    = srow & 3;
    const int arow  = (tid < 128) ? srow : 0;   // clamp: threads >=128 never use A

    const bf16_t* aptr = A + (size_t)(m0 + arow) * DMODEL + shalf * 16;
    const bf16_t* wptr = W + (size_t)(n0 + srow) * DMODEL + shalf * 16;

    f4 acc[4][2];
    #pragma unroll
    for (int i = 0; i < 4; i++)
        #pragma unroll
        for (int j = 0; j < 2; j++)
            acc[i][j] = (f4){0.f, 0.f, 0.f, 0.f};

    for (int k0 = 0; k0 < DMODEL; k0 += 32) {
        uint4 au0, au1, bu0, bu1;
        if (tid < 128) ld_stage(aptr + k0, au0, au1);
        ld_stage(wptr + k0, bu0, bu1);
        __syncthreads();               // previous step's frag reads done
        if (tid < 128) {
            As4[srow * 4 + ((shalf * 2 + 0) ^ sw)] = au0;
            As4[srow * 4 + ((shalf * 2 + 1) ^ sw)] = au1;
        }
        Bs4[srow * 4 + ((shalf * 2 + 0) ^ sw)] = bu0;
        Bs4[srow * 4 + ((shalf * 2 + 1) ^ sw)] = bu1;
        __syncthreads();

        s8 af[4], bf[2];
        #pragma unroll
        for (int t = 0; t < 4; t++) {
            const int ar = t * 16 + l15;
            union { uint4 u; s8 s; } xa;
            xa.u = As4[ar * 4 + (quad ^ (ar & 3))];
            af[t] = xa.s;
        }
        #pragma unroll
        for (int nt = 0; nt < 2; nt++) {
            const int br = w * 32 + nt * 16 + l15;
            union { uint4 u; s8 s; } xb;
            xb.u = Bs4[br * 4 + (quad ^ (br & 3))];
            bf[nt] = xb.s;
        }
        #pragma unroll
        for (int mt = 0; mt < 4; mt++)
            #pragma unroll
            for (int nt = 0; nt < 2; nt++)
                acc[mt][nt] = MFMA(af[mt], bf[nt], acc[mt][nt]);
    }

    // epilogue: row = m0+16mt+4quad+reg, col = n0+32w+16nt+l15
    #pragma unroll
    for (int mt = 0; mt < 4; mt++) {
        #pragma unroll
        for (int nt = 0; nt < 2; nt++) {
            const int col = n0 + w * 32 + nt * 16 + l15;
            const float bb = bias[col];
            #pragma unroll
            for (int reg = 0; reg < 4; reg++) {
                const int row = m0 + mt * 16 + quad * 4 + reg;
                C[(size_t)row * DMODEL + col] = acc[mt][nt][reg] + bb;
            }
        }
    }
}

// ---------------------------------------------------------------------------
// MFMA flash attention — r11 structure (131 us, best measured) with ONE
// change: XCD-AWARE BLOCK SWIZZLE (T1).
// Default dispatch round-robins blockIdx across the 8 XCDs, so the 32
// q-blocks sharing one (h,b)'s K/V land on ALL XCDs -> every XCD re-fetches
// the same 512 KB K/V from L3/HBM (r11 FETCH 53 MB ~ 3x the 18 MB minimum).
// Remap so each XCD owns 3 complete (h,b) groups (768 = 8 x 96 exact,
// bijective): per-XCD working set ~2.3 MB (K+V+Q for 3 groups) fits the
// 4 MB L2 -> K/V fragment loads become L2 hits. The kernel is latency-bound
// on exactly those loads (403 GB/s = 5% HBM, MfmaUtil 8, VALU 34).
// Everything else identical to r11. (Round 14 failed on infra — identical
// failure to r10 which resolved on unmodified resubmit; this IS that
// resubmit. The swizzle is bijective: bid = g + 8j, hb = 3g + j/32,
// q0 = (j%32)*64 covers every (b,h,q0) exactly once.)
// ---------------------------------------------------------------------------
__global__ __launch_bounds__(256) void attn_mfma(
    const bf16_t* __restrict__ Q, const bf16_t* __restrict__ K,
    const bf16_t* __restrict__ V, const unsigned long long* __restrict__ mbits,
    bf16_t* __restrict__ O)
{
    __shared__ unsigned Vs[2][64][36];    // double-buffered V tile [d][kpair]

    const int tid  = threadIdx.x;
    const int lane = tid & 63;
    const int w    = tid >> 6;            // 0..3
    const int l15  = lane & 15;
    const int quad = lane >> 4;

    // XCD swizzle: bid -> (XCD g, local j); XCD g owns (h,b) groups 3g..3g+2
    const int bid = blockIdx.x + (SS / 64) * (blockIdx.y + NHEAD * blockIdx.z);
    const int g   = bid & 7;              // dispatch: block i -> XCD i%8
    const int j   = bid >> 3;             // 0..95 within this XCD
    const int hb  = 3 * g + (j >> 5);     // 0..23
    const int q0  = (j & 31) * 64;
    const int h   = hb % NHEAD;
    const int b   = hb / NHEAD;

    const size_t base = ((size_t)b * SS) * DMODEL + (size_t)h * DKDIM;

    // Q as B-operand (col q = l15); K as A-operand (row k = l15): same loads
    const bf16_t* qrow = Q + base + (size_t)(q0 + w * 16 + l15) * DMODEL + quad * 8;
    const s8 qf0 = ldfrag(qrow);
    const s8 qf1 = ldfrag(qrow + 32);

    f4 oacc[4];
    #pragma unroll
    for (int i = 0; i < 4; i++) oacc[i] = (f4){0.f, 0.f, 0.f, 0.f};
    float l_part = 0.0f;                  // denominator partial for q = l15

    const int kp  = tid & 31;
    const int oct = tid >> 5;
    const bf16_t* vbase = V + base + (size_t)(2 * kp) * DMODEL + oct * 8;
    const bf16_t* kbase = K + base + (size_t)l15 * DMODEL + quad * 8;

    // one u64 mask word per iter: row q = l15 of this wave's q-tile
    const unsigned long long* mbase =
        mbits + ((size_t)b * SS + (q0 + w * 16 + l15)) * MWORDS;

    // loop-invariant shuffle sources + select (verified in r7's passing run)
    const int sA  = l15 + (((2 * quad) & 3) << 4);
    const int sB  = l15 + (((2 * quad + 1) & 3) << 4);
    const bool hiQ = (quad & 2) != 0;

    // prologue: stage V tile 0 into Vs[0], prefetch V tile 1 into regs
    uint4 va = *(const uint4*)(vbase);
    uint4 vb = *(const uint4*)(vbase + DMODEL);
    {
        const unsigned short* pa = (const unsigned short*)&va;
        const unsigned short* pb = (const unsigned short*)&vb;
        #pragma unroll
        for (int i = 0; i < 8; i++)
            Vs[0][oct * 8 + i][kp] = (unsigned)pa[i] | ((unsigned)pb[i] << 16);
    }
    va = *(const uint4*)(vbase + (size_t)64 * DMODEL);
    vb = *(const uint4*)(vbase + (size_t)64 * DMODEL + DMODEL);

    // prologue: prefetch K fragments + mask word for iteration 0
    s8 kf0[4], kf1[4];
    unsigned long long mw;
    #pragma unroll
    for (int nt = 0; nt < 4; nt++) {
        const bf16_t* krow = kbase + (size_t)(nt * 16) * DMODEL;
        kf0[nt] = ldfrag(krow);
        kf1[nt] = ldfrag(krow + 32);
    }
    mw = mbase[0];

    __syncthreads();

    for (int it = 0; it < NIT; ++it) {
        const int k0  = it * 64;
        const int cur = it & 1;

        // stage next V tile from prefetched regs; issue prefetch for it+2
        if (it + 1 < NIT) {
            const unsigned short* pa = (const unsigned short*)&va;
            const unsigned short* pb = (const unsigned short*)&vb;
            #pragma unroll
            for (int i = 0; i < 8; i++)
                Vs[cur ^ 1][oct * 8 + i][kp] = (unsigned)pa[i] | ((unsigned)pb[i] << 16);
            if (it + 2 < NIT) {
                va = *(const uint4*)(vbase + (size_t)(k0 + 128) * DMODEL);
                vb = *(const uint4*)(vbase + (size_t)(k0 + 128) * DMODEL + DMODEL);
            }
        }

        // swapped QK^T on prefetched K fragments: sacc = S^T tiles
        f4 sacc[4];
        __builtin_amdgcn_s_setprio(1);
        #pragma unroll
        for (int nt = 0; nt < 4; nt++) {
            f4 zz = {0.f, 0.f, 0.f, 0.f};
            zz = MFMA(kf0[nt], qf0, zz);
            zz = MFMA(kf1[nt], qf1, zz);
            sacc[nt] = zz;
        }
        __builtin_amdgcn_s_setprio(0);

        // prefetch K fragments + mask word for it+1 (hidden under softmax+PV)
        const unsigned long long mwc = mw;
        if (it + 1 < NIT) {
            #pragma unroll
            for (int nt = 0; nt < 4; nt++) {
                const bf16_t* krow = kbase + (size_t)(k0 + 64 + nt * 16) * DMODEL;
                kf0[nt] = ldfrag(krow);
                kf1[nt] = ldfrag(krow + 32);
            }
            mw = mbase[it + 1];
        }

        // fixed-max softmax: p = maskbit ? exp2(s) : 0, pack k-pairs in-lane.
        // bit for value (nt,reg): position nt*16 + quad*4 + reg of mwc.
        const unsigned ml = ((unsigned)mwc) >> (quad * 4);
        const unsigned mh = ((unsigned)(mwc >> 32)) >> (quad * 4);
        unsigned wlo[4], whi[4];
        #pragma unroll
        for (int nt = 0; nt < 4; nt++) {
            const unsigned mm = (nt & 2) ? mh : ml;
            const int shft = (nt & 1) * 16;
            const float p0 = ((mm >> (shft + 0)) & 1u) ? __builtin_exp2f(sacc[nt][0]) : 0.0f;
            const float p1 = ((mm >> (shft + 1)) & 1u) ? __builtin_exp2f(sacc[nt][1]) : 0.0f;
            const float p2 = ((mm >> (shft + 2)) & 1u) ? __builtin_exp2f(sacc[nt][2]) : 0.0f;
            const float p3 = ((mm >> (shft + 3)) & 1u) ? __builtin_exp2f(sacc[nt][3]) : 0.0f;
            l_part += (p0 + p1) + (p2 + p3);
            wlo[nt] = cvtpk2(p0, p1);
            whi[nt] = cvtpk2(p2, p3);
        }

        // P -> PV A-frag among the 4 lanes sharing l15 (r7-verified), then PV
        #pragma unroll
        for (int kt = 0; kt < 2; kt++) {
            const unsigned a0 = (unsigned)__shfl((int)wlo[2 * kt],     sA, 64);
            const unsigned a1 = (unsigned)__shfl((int)wlo[2 * kt + 1], sA, 64);
            const unsigned b0 = (unsigned)__shfl((int)whi[2 * kt],     sA, 64);
            const unsigned b1 = (unsigned)__shfl((int)whi[2 * kt + 1], sA, 64);
            const unsigned c0 = (unsigned)__shfl((int)wlo[2 * kt],     sB, 64);
            const unsigned c1 = (unsigned)__shfl((int)wlo[2 * kt + 1], sB, 64);
            const unsigned d0 = (unsigned)__shfl((int)whi[2 * kt],     sB, 64);
            const unsigned d1 = (unsigned)__shfl((int)whi[2 * kt + 1], sB, 64);
            union { uint4 u; s8 s; } pf;
            pf.u.x = hiQ ? a1 : a0;
            pf.u.y = hiQ ? b1 : b0;
            pf.u.z = hiQ ? c1 : c0;
            pf.u.w = hiQ ? d1 : d0;

            __builtin_amdgcn_s_setprio(1);
            #pragma unroll
            for (int dt = 0; dt < 4; dt++) {
                union { uint4 u; s8 s; } vf;
                vf.u = *(const uint4*)&Vs[cur][dt * 16 + l15][kt * 16 + quad * 4];
                oacc[dt] = MFMA(pf.s, vf.s, oacc[dt]);
            }
            __builtin_amdgcn_s_setprio(0);
        }

        __syncthreads();   // Vs[cur] reads done; Vs[cur^1] writes visible
    }

    // epilogue: reduce l over quads (q = l15), redistribute, normalize, store
    l_part += __shfl_xor(l_part, 16, 64);
    l_part += __shfl_xor(l_part, 32, 64);
    const float inv = 1.0f / l_part;      // valid for q-row l15

    #pragma unroll
    for (int reg = 0; reg < 4; reg++) {
        const float invq = __shfl(inv, (quad << 4) + quad * 4 + reg, 64);
        const size_t row = q0 + w * 16 + quad * 4 + reg;
        #pragma unroll
        for (int dt = 0; dt < 4; dt++) {
            O[base + row * DMODEL + dt * 16 + l15] = f2bf(oacc[dt][reg] * invq);
        }
    }
}

// ---------------------------------------------------------------------------
extern "C" void kernel_launch(void* const* d_in, const int* in_sizes, int n_in,
                              void* d_out, int out_size, void* d_ws, size_t ws_size,
                              hipStream_t stream)
{
    const float* q    = (const float*)d_in[0];
    const float* k    = (const float*)d_in[1];
    const float* v    = (const float*)d_in[2];
    const int*   mask = (const int*)  d_in[3];
    const float* Wq   = (const float*)d_in[4];
    const float* bq   = (const float*)d_in[5];
    const float* Wk   = (const float*)d_in[6];
    const float* bk   = (const float*)d_in[7];
    const float* Wv   = (const float*)d_in[8];
    const float* bv   = (const float*)d_in[9];
    const float* Wo   = (const float*)d_in[10];
    const float* bo   = (const float*)d_in[11];
    float* out = (float*)d_out;

    // workspace (~50 MB): 4 bf16 planes (25.2 MB) + 4 bf16 weights (4.7 MB)
    //                    + 3 bf16 input planes (18.9 MB) + mbits (1 MB)
    bf16_t* wsb = (bf16_t*)d_ws;
    const size_t plane = (size_t)MROWS * DMODEL;   // 3,145,728
    bf16_t* Qp  = wsb;
    bf16_t* Kp  = wsb + plane;
    bf16_t* Vp  = wsb + 2 * plane;
    bf16_t* Ctx = wsb + 3 * plane;
    bf16_t* Wqb = wsb + 4 * plane;
    bf16_t* Wkb = Wqb + WELEM;
    bf16_t* Wvb = Wkb + WELEM;
    bf16_t* Wob = Wvb + WELEM;
    bf16_t* Abf = Wob + WELEM;            // 3 bf16 input planes
    unsigned long long* mbits = (unsigned long long*)(Abf + 3 * plane);

    cvt_weights<<<dim3(WELEM / 1024, 4), 256, 0, stream>>>(Wq, Wk, Wv, Wo, Wqb);
    cvt_inputs<<<dim3((int)(plane / 1024), 3), 256, 0, stream>>>(q, k, v, Abf);
    mask_to_bits<<<dim3((BB * SS * SS) / 256), 256, 0, stream>>>(mask, mbits);

    // fused Q/K/V projections (BK=32, gload_lds staging — r8/r11 version);
    // Q pre-scaled by 0.125*log2(e) for the exp2 softmax
    gemm_qkv<<<dim3(DMODEL / 128, MROWS / 128, 3), 256, 0, stream>>>(
        Abf, Abf + plane, Abf + 2 * plane, Wqb, Wkb, Wvb, bq, bk, bv,
        Qp, Kp, Vp, 0.125f * 1.44269504f, 1.0f, 1.0f);

    // swapped-QK flash attention + XCD swizzle: grid (32, 12, 2), 256 thr
    attn_mfma<<<dim3(SS / 64, NHEAD, BB), 256, 0, stream>>>(Qp, Kp, Vp, mbits, Ctx);

    // output projection: 64x128 tile, grid (6, 64) = 384 blocks (1.5/CU)
    gemm_out<<<dim3(DMODEL / 128, MROWS / 64), 256, 0, stream>>>(Ctx, Wob, bo, out);
}

// Round 16
// 306.058 us; speedup vs baseline: 1.2453x; 1.0011x over previous
//
#include <hip/hip_runtime.h>
#include <math.h>

#define DMODEL 768
#define NHEAD 12
#define DKDIM 64
#define BB 2
#define SS 2048
#define MROWS (BB * SS)          // 4096
#define WELEM (DMODEL * DMODEL)  // 589824
#define MWORDS (SS / 64)         // 32 u64 mask words per row
#define NIT (SS / 64)            // 32 K-tiles

typedef unsigned short bf16_t;
typedef __attribute__((ext_vector_type(8))) short s8;   // 8 bf16 = 4 VGPRs (MFMA A/B frag)
typedef __attribute__((ext_vector_type(4))) short s4;   // 4 bf16 = 2 VGPRs (K=16 MFMA frag)
typedef __attribute__((ext_vector_type(4))) float f4;   // MFMA C/D frag

#define MFMA(a, b, c) __builtin_amdgcn_mfma_f32_16x16x32_bf16((a), (b), (c), 0, 0, 0)

// K=16 bf16 MFMA: A-frag layout k = quad*4+j matches the 16x16 C-layout's
// row indexing exactly -> the softmax output feeds PV with NO cross-lane ops.
#if defined(__has_builtin)
#  if __has_builtin(__builtin_amdgcn_mfma_f32_16x16x16bf16_1k)
#    define HAVE_MFMA16 1
#  endif
#endif
#ifndef HAVE_MFMA16
#  define HAVE_MFMA16 0
#endif
#if HAVE_MFMA16
#  define MFMA16(a, b, c) __builtin_amdgcn_mfma_f32_16x16x16bf16_1k((a), (b), (c), 0, 0, 0)
#endif

__device__ __forceinline__ bf16_t f2bf(float f) {   // round-to-nearest-even
    unsigned u = __float_as_uint(f);
    u += 0x7fffu + ((u >> 16) & 1u);
    return (bf16_t)(u >> 16);
}
// HW packed cvt: attention P-pack only (r6: hurts GEMM staging scheduling).
__device__ __forceinline__ unsigned cvtpk2(float a, float b) {
    unsigned r;
    asm("v_cvt_pk_bf16_f32 %0, %1, %2" : "=v"(r) : "v"(a), "v"(b));
    return r;   // lo = bf16(a), hi = bf16(b)
}
__device__ __forceinline__ s8 ldfrag(const bf16_t* p) {
    union { uint4 u; s8 s; } x;
    x.u = *(const uint4*)p;
    return x.s;
}
// async global->LDS, 16B per lane: LDS dest = wave-uniform base + lane*16.
__device__ __forceinline__ void gload16(const bf16_t* g, bf16_t* l) {
    __builtin_amdgcn_global_load_lds(
        (__attribute__((address_space(1))) void*)g,
        (__attribute__((address_space(3))) void*)l,
        16, 0, 0);
}

// stage 16 consecutive bf16 -> 2 x uint4 (reg-staging path)
__device__ __forceinline__ void ld_stage(const bf16_t* p, uint4& u0, uint4& u1) {
    u0 = *(const uint4*)p;
    u1 = *(const uint4*)(p + 8);
}

// ---------------------------------------------------------------------------
// Weight prepass: fp32 -> bf16, 4 matrices of 768x768. grid (576, 4), 256 thr.
// ---------------------------------------------------------------------------
__global__ void cvt_weights(const float* __restrict__ W0, const float* __restrict__ W1,
                            const float* __restrict__ W2, const float* __restrict__ W3,
                            bf16_t* __restrict__ dst)
{
    const float* src = (blockIdx.y == 0) ? W0 : (blockIdx.y == 1) ? W1
                     : (blockIdx.y == 2) ? W2 : W3;
    bf16_t* d = dst + (size_t)blockIdx.y * WELEM;
    const int i = (blockIdx.x * 256 + threadIdx.x) * 4;
    const float4 v = *(const float4*)(src + i);
    ushort4 h;
    h.x = f2bf(v.x); h.y = f2bf(v.y); h.z = f2bf(v.z); h.w = f2bf(v.w);
    *(ushort4*)(d + i) = h;
}

// ---------------------------------------------------------------------------
// Input prepass: fp32 -> bf16 once (QKV GEMM stages via global_load_lds,
// which cannot convert). grid (3072, 3), 256 thr.
// ---------------------------------------------------------------------------
__global__ __launch_bounds__(256) void cvt_inputs(
    const float* __restrict__ A0, const float* __restrict__ A1,
    const float* __restrict__ A2, bf16_t* __restrict__ dst)
{
    const float* src = (blockIdx.y == 0) ? A0 : (blockIdx.y == 1) ? A1 : A2;
    bf16_t* d = dst + (size_t)blockIdx.y * MROWS * DMODEL;
    const int i = (blockIdx.x * 256 + threadIdx.x) * 4;
    const float4 v = *(const float4*)(src + i);
    ushort4 h;
    h.x = f2bf(v.x); h.y = f2bf(v.y); h.z = f2bf(v.z); h.w = f2bf(v.w);
    *(ushort4*)(d + i) = h;
}

// ---------------------------------------------------------------------------
// Mask prepass: int32 [B,S,S] -> bit-packed u64 words (1 MB, L2-resident).
// ---------------------------------------------------------------------------
__global__ __launch_bounds__(256) void mask_to_bits(
    const int* __restrict__ mask, unsigned long long* __restrict__ mbits)
{
    const size_t gid = (size_t)blockIdx.x * 256 + threadIdx.x;
    const int m = mask[gid];
    const unsigned long long bal = __ballot(m != 0);
    if ((threadIdx.x & 63) == 0) mbits[gid >> 6] = bal;
}

// ---------------------------------------------------------------------------
// QKV GEMM — r8/r11 version (best measured): 128x128 tile, BK=32 +
// global_load_lds staging. G21 both-sides swizzle: linear LDS dest +
// pre-swizzled per-lane source (blk^(row&3)) + swizzled frag read.
// grid (6, 32, 3) = 576 blocks, 2.25/CU.
// ---------------------------------------------------------------------------
__global__ __launch_bounds__(256) void gemm_qkv(
    const bf16_t* __restrict__ A0, const bf16_t* __restrict__ A1, const bf16_t* __restrict__ A2,
    const bf16_t* __restrict__ W0, const bf16_t* __restrict__ W1, const bf16_t* __restrict__ W2,
    const float* __restrict__ bias0, const float* __restrict__ bias1, const float* __restrict__ bias2,
    bf16_t* __restrict__ C0, bf16_t* __restrict__ C1, bf16_t* __restrict__ C2,
    float sc0, float sc1, float sc2)
{
    __shared__ uint4 As4[128 * 4];   // 8 KB, [row][swizzled 16B blk]
    __shared__ uint4 Bs4[128 * 4];

    const int z = blockIdx.z;
    const bf16_t* A    = (z == 0) ? A0 : (z == 1) ? A1 : A2;
    const bf16_t* W    = (z == 0) ? W0 : (z == 1) ? W1 : W2;
    const float*  bias = (z == 0) ? bias0 : (z == 1) ? bias1 : bias2;
    bf16_t*       C    = (z == 0) ? C0 : (z == 1) ? C1 : C2;
    const float   sc   = (z == 0) ? sc0 : (z == 1) ? sc1 : sc2;

    const int tid  = threadIdx.x;
    const int lane = tid & 63;
    const int w    = tid >> 6;
    const int wm   = w & 1;
    const int wn   = w >> 1;
    const int l15  = lane & 15;
    const int quad = lane >> 4;
    const int m0   = blockIdx.y * 128;
    const int n0   = blockIdx.x * 128;

    // per-lane staging sources (pre-swizzled), wave-uniform LDS dests
    const int r0 = tid >> 2,         s0 = (tid & 3) ^ (r0 & 3);
    const int r1 = 64 + (tid >> 2),  s1 = (tid & 3) ^ (r1 & 3);
    const bf16_t* aS0 = A + (size_t)(m0 + r0) * DMODEL + s0 * 8;
    const bf16_t* aS1 = A + (size_t)(m0 + r1) * DMODEL + s1 * 8;
    const bf16_t* wS0 = W + (size_t)(n0 + r0) * DMODEL + s0 * 8;
    const bf16_t* wS1 = W + (size_t)(n0 + r1) * DMODEL + s1 * 8;
    bf16_t* aD0 = (bf16_t*)As4 + w * 512;          // issue 0: chunks 0..255
    bf16_t* aD1 = (bf16_t*)As4 + 2048 + w * 512;   // issue 1: chunks 256..511
    bf16_t* bD0 = (bf16_t*)Bs4 + w * 512;
    bf16_t* bD1 = (bf16_t*)Bs4 + 2048 + w * 512;

    f4 acc[4][4];
    #pragma unroll
    for (int i = 0; i < 4; i++)
        #pragma unroll
        for (int j = 0; j < 4; j++)
            acc[i][j] = (f4){0.f, 0.f, 0.f, 0.f};

    for (int k0 = 0; k0 < DMODEL; k0 += 32) {
        __syncthreads();               // previous iteration's frag reads done
        gload16(aS0 + k0, aD0);
        gload16(aS1 + k0, aD1);
        gload16(wS0 + k0, bD0);
        gload16(wS1 + k0, bD1);
        __syncthreads();               // compiler drains vmcnt(0) before barrier

        s8 af[4], bf[4];
        #pragma unroll
        for (int t = 0; t < 4; t++) {
            const int ar = wm * 64 + t * 16 + l15;
            const int br = wn * 64 + t * 16 + l15;
            union { uint4 u; s8 s; } xa, xb;
            xa.u = As4[ar * 4 + (quad ^ (ar & 3))];
            xb.u = Bs4[br * 4 + (quad ^ (br & 3))];
            af[t] = xa.s;
            bf[t] = xb.s;
        }
        #pragma unroll
        for (int mt = 0; mt < 4; mt++)
            #pragma unroll
            for (int nt = 0; nt < 4; nt++)
                acc[mt][nt] = MFMA(af[mt], bf[nt], acc[mt][nt]);
    }

    // epilogue: row = m0+64wm+16mt+4quad+reg, col = n0+64wn+16nt+l15
    #pragma unroll
    for (int mt = 0; mt < 4; mt++) {
        #pragma unroll
        for (int nt = 0; nt < 4; nt++) {
            const int col = n0 + wn * 64 + nt * 16 + l15;
            const float bb = bias[col];
            #pragma unroll
            for (int reg = 0; reg < 4; reg++) {
                const int row = m0 + wm * 64 + mt * 16 + quad * 4 + reg;
                C[(size_t)row * DMODEL + col] = f2bf((acc[mt][nt][reg] + bb) * sc);
            }
        }
    }
}

// ---------------------------------------------------------------------------
// Output-projection GEMM — r11 version (verified win): 64x128 tile,
// grid (6, 64) = 384 blocks (1.5/CU), reg-staged BK=32 with XOR swizzle.
// ---------------------------------------------------------------------------
__global__ __launch_bounds__(256) void gemm_out(
    const bf16_t* __restrict__ A, const bf16_t* __restrict__ W,
    const float* __restrict__ bias, float* __restrict__ C)
{
    __shared__ uint4 As4[64 * 4];    // 4 KB
    __shared__ uint4 Bs4[128 * 4];   // 8 KB

    const int tid  = threadIdx.x;
    const int lane = tid & 63;
    const int w    = tid >> 6;       // 0..3: 32-col strip
    const int l15  = lane & 15;
    const int quad = lane >> 4;
    const int m0   = blockIdx.y * 64;
    const int n0   = blockIdx.x * 128;

    const int srow  = tid >> 1;      // 0..127 (B rows; A uses 0..63)
    const int shalf = tid & 1;
    const int sw    = srow & 3;
    const int arow  = (tid < 128) ? srow : 0;   // clamp: threads >=128 never use A

    const bf16_t* aptr = A + (size_t)(m0 + arow) * DMODEL + shalf * 16;
    const bf16_t* wptr = W + (size_t)(n0 + srow) * DMODEL + shalf * 16;

    f4 acc[4][2];
    #pragma unroll
    for (int i = 0; i < 4; i++)
        #pragma unroll
        for (int j = 0; j < 2; j++)
            acc[i][j] = (f4){0.f, 0.f, 0.f, 0.f};

    for (int k0 = 0; k0 < DMODEL; k0 += 32) {
        uint4 au0, au1, bu0, bu1;
        if (tid < 128) ld_stage(aptr + k0, au0, au1);
        ld_stage(wptr + k0, bu0, bu1);
        __syncthreads();               // previous step's frag reads done
        if (tid < 128) {
            As4[srow * 4 + ((shalf * 2 + 0) ^ sw)] = au0;
            As4[srow * 4 + ((shalf * 2 + 1) ^ sw)] = au1;
        }
        Bs4[srow * 4 + ((shalf * 2 + 0) ^ sw)] = bu0;
        Bs4[srow * 4 + ((shalf * 2 + 1) ^ sw)] = bu1;
        __syncthreads();

        s8 af[4], bf[2];
        #pragma unroll
        for (int t = 0; t < 4; t++) {
            const int ar = t * 16 + l15;
            union { uint4 u; s8 s; } xa;
            xa.u = As4[ar * 4 + (quad ^ (ar & 3))];
            af[t] = xa.s;
        }
        #pragma unroll
        for (int nt = 0; nt < 2; nt++) {
            const int br = w * 32 + nt * 16 + l15;
            union { uint4 u; s8 s; } xb;
            xb.u = Bs4[br * 4 + (quad ^ (br & 3))];
            bf[nt] = xb.s;
        }
        #pragma unroll
        for (int mt = 0; mt < 4; mt++)
            #pragma unroll
            for (int nt = 0; nt < 2; nt++)
                acc[mt][nt] = MFMA(af[mt], bf[nt], acc[mt][nt]);
    }

    // epilogue: row = m0+16mt+4quad+reg, col = n0+32w+16nt+l15
    #pragma unroll
    for (int mt = 0; mt < 4; mt++) {
        #pragma unroll
        for (int nt = 0; nt < 2; nt++) {
            const int col = n0 + w * 32 + nt * 16 + l15;
            const float bb = bias[col];
            #pragma unroll
            for (int reg = 0; reg < 4; reg++) {
                const int row = m0 + mt * 16 + quad * 4 + reg;
                C[(size_t)row * DMODEL + col] = acc[mt][nt][reg] + bb;
            }
        }
    }
}

// ---------------------------------------------------------------------------
// MFMA flash attention — r15 structure + XCD swizzle (kept: FETCH 53->11 MB)
// with ONE change: the P -> PV cross-lane redistribution (16 ds_bpermute +
// 8 cndmask per iter) is DELETED by switching PV to 16x16x16 MFMAs.
// r15 proved the kernel time-insensitive to memory (4.7x fetch drop, 0 time
// delta) -> the stall is the in-register/DS serial chain. The K=16 A-frag
// layout (k = quad*4+j) exactly matches the S^T C-layout (k = quad*4+reg),
// so pk = {cvtpk2(p0,p1), cvtpk2(p2,p3)} IS the PV A-fragment. B-frag is one
// ds_read_b64 from the existing Vs layout (lane l15 = d, kpairs nt*8+quad*2;
// 2-way bank alias = free). 16 MFMA16/iter replace 8 MFMA32 (equal FLOPs).
// Guarded by __has_builtin: if the 1k builtin is absent, falls back to the
// r15 shuffle path (no worse than 306 us).
// Everything else identical to r15: swapped QK^T, bit-mask (1 u64/iter),
// fixed-max exp2 softmax (Q pre-scaled 0.125*log2e), K/mask prefetch one
// iter ahead, V double-buffered in LDS (1 barrier/iter), setprio, XCD swizzle.
// ---------------------------------------------------------------------------
__global__ __launch_bounds__(256) void attn_mfma(
    const bf16_t* __restrict__ Q, const bf16_t* __restrict__ K,
    const bf16_t* __restrict__ V, const unsigned long long* __restrict__ mbits,
    bf16_t* __restrict__ O)
{
    __shared__ unsigned Vs[2][64][36];    // double-buffered V tile [d][kpair]

    const int tid  = threadIdx.x;
    const int lane = tid & 63;
    const int w    = tid >> 6;            // 0..3
    const int l15  = lane & 15;
    const int quad = lane >> 4;

    // XCD swizzle: bid -> (XCD g, local j); XCD g owns (h,b) groups 3g..3g+2
    const int bid = blockIdx.x + (SS / 64) * (blockIdx.y + NHEAD * blockIdx.z);
    const int g   = bid & 7;              // dispatch: block i -> XCD i%8
    const int j   = bid >> 3;             // 0..95 within this XCD
    const int hb  = 3 * g + (j >> 5);     // 0..23
    const int q0  = (j & 31) * 64;
    const int h   = hb % NHEAD;
    const int b   = hb / NHEAD;

    const size_t base = ((size_t)b * SS) * DMODEL + (size_t)h * DKDIM;

    // Q as B-operand (col q = l15); K as A-operand (row k = l15): same loads
    const bf16_t* qrow = Q + base + (size_t)(q0 + w * 16 + l15) * DMODEL + quad * 8;
    const s8 qf0 = ldfrag(qrow);
    const s8 qf1 = ldfrag(qrow + 32);

    f4 oacc[4];
    #pragma unroll
    for (int i = 0; i < 4; i++) oacc[i] = (f4){0.f, 0.f, 0.f, 0.f};
    float l_part = 0.0f;                  // denominator partial for q = l15

    const int kp  = tid & 31;
    const int oct = tid >> 5;
    const bf16_t* vbase = V + base + (size_t)(2 * kp) * DMODEL + oct * 8;
    const bf16_t* kbase = K + base + (size_t)l15 * DMODEL + quad * 8;

    // one u64 mask word per iter: row q = l15 of this wave's q-tile
    const unsigned long long* mbase =
        mbits + ((size_t)b * SS + (q0 + w * 16 + l15)) * MWORDS;

    // loop-invariant shuffle sources + select (fallback path only)
    const int sA  = l15 + (((2 * quad) & 3) << 4);
    const int sB  = l15 + (((2 * quad + 1) & 3) << 4);
    const bool hiQ = (quad & 2) != 0;
    (void)sA; (void)sB; (void)hiQ;

    // prologue: stage V tile 0 into Vs[0], prefetch V tile 1 into regs
    uint4 va = *(const uint4*)(vbase);
    uint4 vb = *(const uint4*)(vbase + DMODEL);
    {
        const unsigned short* pa = (const unsigned short*)&va;
        const unsigned short* pb = (const unsigned short*)&vb;
        #pragma unroll
        for (int i = 0; i < 8; i++)
            Vs[0][oct * 8 + i][kp] = (unsigned)pa[i] | ((unsigned)pb[i] << 16);
    }
    va = *(const uint4*)(vbase + (size_t)64 * DMODEL);
    vb = *(const uint4*)(vbase + (size_t)64 * DMODEL + DMODEL);

    // prologue: prefetch K fragments + mask word for iteration 0
    s8 kf0[4], kf1[4];
    unsigned long long mw;
    #pragma unroll
    for (int nt = 0; nt < 4; nt++) {
        const bf16_t* krow = kbase + (size_t)(nt * 16) * DMODEL;
        kf0[nt] = ldfrag(krow);
        kf1[nt] = ldfrag(krow + 32);
    }
    mw = mbase[0];

    __syncthreads();

    for (int it = 0; it < NIT; ++it) {
        const int k0  = it * 64;
        const int cur = it & 1;

        // stage next V tile from prefetched regs; issue prefetch for it+2
        if (it + 1 < NIT) {
            const unsigned short* pa = (const unsigned short*)&va;
            const unsigned short* pb = (const unsigned short*)&vb;
            #pragma unroll
            for (int i = 0; i < 8; i++)
                Vs[cur ^ 1][oct * 8 + i][kp] = (unsigned)pa[i] | ((unsigned)pb[i] << 16);
            if (it + 2 < NIT) {
                va = *(const uint4*)(vbase + (size_t)(k0 + 128) * DMODEL);
                vb = *(const uint4*)(vbase + (size_t)(k0 + 128) * DMODEL + DMODEL);
            }
        }

        // swapped QK^T on prefetched K fragments: sacc = S^T tiles
        f4 sacc[4];
        __builtin_amdgcn_s_setprio(1);
        #pragma unroll
        for (int nt = 0; nt < 4; nt++) {
            f4 zz = {0.f, 0.f, 0.f, 0.f};
            zz = MFMA(kf0[nt], qf0, zz);
            zz = MFMA(kf1[nt], qf1, zz);
            sacc[nt] = zz;
        }
        __builtin_amdgcn_s_setprio(0);

        // prefetch K fragments + mask word for it+1 (hidden under softmax+PV)
        const unsigned long long mwc = mw;
        if (it + 1 < NIT) {
            #pragma unroll
            for (int nt = 0; nt < 4; nt++) {
                const bf16_t* krow = kbase + (size_t)(k0 + 64 + nt * 16) * DMODEL;
                kf0[nt] = ldfrag(krow);
                kf1[nt] = ldfrag(krow + 32);
            }
            mw = mbase[it + 1];
        }

        // fixed-max softmax: p = maskbit ? exp2(s) : 0.
        // bit for value (nt,reg): position nt*16 + quad*4 + reg of mwc.
        const unsigned ml = ((unsigned)mwc) >> (quad * 4);
        const unsigned mh = ((unsigned)(mwc >> 32)) >> (quad * 4);

#if HAVE_MFMA16
        // pk IS the PV A-fragment (K=16 layout k=quad*4+j == C-layout rows);
        // PV per nt: 4 x mfma_16x16x16, B-frag = ds_read_b64 of Vs kpairs.
        #pragma unroll
        for (int nt = 0; nt < 4; nt++) {
            const unsigned mm = (nt & 2) ? mh : ml;
            const int shft = (nt & 1) * 16;
            const float p0 = ((mm >> (shft + 0)) & 1u) ? __builtin_exp2f(sacc[nt][0]) : 0.0f;
            const float p1 = ((mm >> (shft + 1)) & 1u) ? __builtin_exp2f(sacc[nt][1]) : 0.0f;
            const float p2 = ((mm >> (shft + 2)) & 1u) ? __builtin_exp2f(sacc[nt][2]) : 0.0f;
            const float p3 = ((mm >> (shft + 3)) & 1u) ? __builtin_exp2f(sacc[nt][3]) : 0.0f;
            l_part += (p0 + p1) + (p2 + p3);
            union { unsigned u[2]; s4 s; } pk;
            pk.u[0] = cvtpk2(p0, p1);
            pk.u[1] = cvtpk2(p2, p3);

            __builtin_amdgcn_s_setprio(1);
            #pragma unroll
            for (int dt = 0; dt < 4; dt++) {
                union { uint2 u; s4 s; } vf;
                vf.u = *(const uint2*)&Vs[cur][dt * 16 + l15][nt * 8 + quad * 2];
                oacc[dt] = MFMA16(pk.s, vf.s, oacc[dt]);
            }
            __builtin_amdgcn_s_setprio(0);
        }
#else
        // fallback: r15 shuffle-PV path (16 __shfl + 8 cndmask per iter)
        unsigned wlo[4], whi[4];
        #pragma unroll
        for (int nt = 0; nt < 4; nt++) {
            const unsigned mm = (nt & 2) ? mh : ml;
            const int shft = (nt & 1) * 16;
            const float p0 = ((mm >> (shft + 0)) & 1u) ? __builtin_exp2f(sacc[nt][0]) : 0.0f;
            const float p1 = ((mm >> (shft + 1)) & 1u) ? __builtin_exp2f(sacc[nt][1]) : 0.0f;
            const float p2 = ((mm >> (shft + 2)) & 1u) ? __builtin_exp2f(sacc[nt][2]) : 0.0f;
            const float p3 = ((mm >> (shft + 3)) & 1u) ? __builtin_exp2f(sacc[nt][3]) : 0.0f;
            l_part += (p0 + p1) + (p2 + p3);
            wlo[nt] = cvtpk2(p0, p1);
            whi[nt] = cvtpk2(p2, p3);
        }
        #pragma unroll
        for (int kt = 0; kt < 2; kt++) {
            const unsigned a0 = (unsigned)__shfl((int)wlo[2 * kt],     sA, 64);
            const unsigned a1 = (unsigned)__shfl((int)wlo[2 * kt + 1], sA, 64);
            const unsigned b0 = (unsigned)__shfl((int)whi[2 * kt],     sA, 64);
            const unsigned b1 = (unsigned)__shfl((int)whi[2 * kt + 1], sA, 64);
            const unsigned c0 = (unsigned)__shfl((int)wlo[2 * kt],     sB, 64);
            const unsigned c1 = (unsigned)__shfl((int)wlo[2 * kt + 1], sB, 64);
            const unsigned d0 = (unsigned)__shfl((int)whi[2 * kt],     sB, 64);
            const unsigned d1 = (unsigned)__shfl((int)whi[2 * kt + 1], sB, 64);
            union { uint4 u; s8 s; } pf;
            pf.u.x = hiQ ? a1 : a0;
            pf.u.y = hiQ ? b1 : b0;
            pf.u.z = hiQ ? c1 : c0;
            pf.u.w = hiQ ? d1 : d0;

            __builtin_amdgcn_s_setprio(1);
            #pragma unroll
            for (int dt = 0; dt < 4; dt++) {
                union { uint4 u; s8 s; } vf;
                vf.u = *(const uint4*)&Vs[cur][dt * 16 + l15][kt * 16 + quad * 4];
                oacc[dt] = MFMA(pf.s, vf.s, oacc[dt]);
            }
            __builtin_amdgcn_s_setprio(0);
        }
#endif

        __syncthreads();   // Vs[cur] reads done; Vs[cur^1] writes visible
    }

    // epilogue: reduce l over quads (q = l15), redistribute, normalize, store
    l_part += __shfl_xor(l_part, 16, 64);
    l_part += __shfl_xor(l_part, 32, 64);
    const float inv = 1.0f / l_part;      // valid for q-row l15

    #pragma unroll
    for (int reg = 0; reg < 4; reg++) {
        const float invq = __shfl(inv, (quad << 4) + quad * 4 + reg, 64);
        const size_t row = q0 + w * 16 + quad * 4 + reg;
        #pragma unroll
        for (int dt = 0; dt < 4; dt++) {
            O[base + row * DMODEL + dt * 16 + l15] = f2bf(oacc[dt][reg] * invq);
        }
    }
}

// ---------------------------------------------------------------------------
extern "C" void kernel_launch(void* const* d_in, const int* in_sizes, int n_in,
                              void* d_out, int out_size, void* d_ws, size_t ws_size,
                              hipStream_t stream)
{
    const float* q    = (const float*)d_in[0];
    const float* k    = (const float*)d_in[1];
    const float* v    = (const float*)d_in[2];
    const int*   mask = (const int*)  d_in[3];
    const float* Wq   = (const float*)d_in[4];
    const float* bq   = (const float*)d_in[5];
    const float* Wk   = (const float*)d_in[6];
    const float* bk   = (const float*)d_in[7];
    const float* Wv   = (const float*)d_in[8];
    const float* bv   = (const float*)d_in[9];
    const float* Wo   = (const float*)d_in[10];
    const float* bo   = (const float*)d_in[11];
    float* out = (float*)d_out;

    // workspace (~50 MB): 4 bf16 planes (25.2 MB) + 4 bf16 weights (4.7 MB)
    //                    + 3 bf16 input planes (18.9 MB) + mbits (1 MB)
    bf16_t* wsb = (bf16_t*)d_ws;
    const size_t plane = (size_t)MROWS * DMODEL;   // 3,145,728
    bf16_t* Qp  = wsb;
    bf16_t* Kp  = wsb + plane;
    bf16_t* Vp  = wsb + 2 * plane;
    bf16_t* Ctx = wsb + 3 * plane;
    bf16_t* Wqb = wsb + 4 * plane;
    bf16_t* Wkb = Wqb + WELEM;
    bf16_t* Wvb = Wkb + WELEM;
    bf16_t* Wob = Wvb + WELEM;
    bf16_t* Abf = Wob + WELEM;            // 3 bf16 input planes
    unsigned long long* mbits = (unsigned long long*)(Abf + 3 * plane);

    cvt_weights<<<dim3(WELEM / 1024, 4), 256, 0, stream>>>(Wq, Wk, Wv, Wo, Wqb);
    cvt_inputs<<<dim3((int)(plane / 1024), 3), 256, 0, stream>>>(q, k, v, Abf);
    mask_to_bits<<<dim3((BB * SS * SS) / 256), 256, 0, stream>>>(mask, mbits);

    // fused Q/K/V projections (BK=32, gload_lds staging — r8/r11 version);
    // Q pre-scaled by 0.125*log2(e) for the exp2 softmax
    gemm_qkv<<<dim3(DMODEL / 128, MROWS / 128, 3), 256, 0, stream>>>(
        Abf, Abf + plane, Abf + 2 * plane, Wqb, Wkb, Wvb, bq, bk, bv,
        Qp, Kp, Vp, 0.125f * 1.44269504f, 1.0f, 1.0f);

    // swapped-QK flash attention (K=16 PV, no cross-lane P): grid (32, 12, 2)
    attn_mfma<<<dim3(SS / 64, NHEAD, BB), 256, 0, stream>>>(Qp, Kp, Vp, mbits, Ctx);

    // output projection: 64x128 tile, grid (6, 64) = 384 blocks (1.5/CU)
    gemm_out<<<dim3(DMODEL / 128, MROWS / 64), 256, 0, stream>>>(Ctx, Wob, bo, out);
}